// Round 5
// baseline (615.650 us; speedup 1.0000x reference)
//
#include <hip/hip_runtime.h>

#define N_NODES 50000
#define N_EDGES 800000
#define IN_DIM 96
#define OUT_DIM 96
#define EDGE_DIM 32
#define BN_EPS 1e-5f

// ws layout (floats): [0 .. 4800000) aggr, later reused as h2 (aliased safely)
//                     [4800000 .. 4800192) BN stats (sum, sumsq)
//                     [4800192]            edge_index-dtype flag (1 = int64)
#define WS_STATS 4800000
#define WS_FLAG 4800192

// ---------------------------------------------------------------------------
// Kernel 0: detect edge_index storage width. Reference declares int64; harness
// may narrow to int32. Viewed as int32, int64 data (values in [0,50000)) has
// EVERY odd element == 0; genuine int32 data has ~uniform values there.
// Sample 16384 odd positions (all < 1.6M, in-bounds under either layout).
// ---------------------------------------------------------------------------
__global__ void detect_kernel(const int* __restrict__ ei, int* __restrict__ flag) {
    __shared__ int any_nonzero;
    if (threadIdx.x == 0) any_nonzero = 0;
    __syncthreads();
    int nz = 0;
    for (int q = 0; q < 64; ++q) {
        int p = 1 + 2 * (threadIdx.x * 64 + q) * 48;  // odd, < 1,572,800
        if (ei[p] != 0) nz = 1;
    }
    if (nz) atomicOr(&any_nonzero, 1);
    __syncthreads();
    if (threadIdx.x == 0) *flag = any_nonzero ? 0 : 1;
}

// ---------------------------------------------------------------------------
// Kernel 1: per-edge message + scatter-add (fp32).
// Block = 4 slots x 96 threads. Thread j (= tid%96) holds We column j in
// registers (32 fp32, loaded once). edge_attr row staged in LDS per slot.
// msg = relu(x[src] + edge_attr@We + be); atomicAdd into aggr[dst].
// ---------------------------------------------------------------------------
#define ESLOTS 4
#define EBLOCK (ESLOTS * 96)

__global__ __launch_bounds__(EBLOCK) void edge_kernel(
    const float* __restrict__ x, const int* __restrict__ ei,
    const float* __restrict__ ea, const float* __restrict__ We,
    const float* __restrict__ be, float* __restrict__ aggr,
    const int* __restrict__ flag) {
    const int tid = threadIdx.x;
    const int slot = tid / 96;
    const int j = tid - slot * 96;
    const int is64 = *flag;  // wave-uniform

    float w[EDGE_DIM];
#pragma unroll
    for (int k = 0; k < EDGE_DIM; ++k) w[k] = We[k * 96 + j];
    const float bej = be[j];

    __shared__ float ea_s[ESLOTS][EDGE_DIM];

    for (long e0 = (long)blockIdx.x * ESLOTS; e0 < N_EDGES;
         e0 += (long)gridDim.x * ESLOTS) {
        const int e = (int)e0 + slot;
        const bool valid = (e < N_EDGES);
        if (valid && j < EDGE_DIM) ea_s[slot][j] = ea[e * EDGE_DIM + j];
        __syncthreads();
        if (valid) {
            float acc = bej;
#pragma unroll
            for (int k = 0; k < EDGE_DIM; ++k) acc += ea_s[slot][k] * w[k];
            int s, d;
            if (is64) {
                s = ei[2 * e];
                d = ei[2 * N_EDGES + 2 * e];
            } else {
                s = ei[e];
                d = ei[N_EDGES + e];
            }
            if (s >= 0 && s < N_NODES && d >= 0 && d < N_NODES) {
                float m = acc + x[s * 96 + j];
                m = m > 0.f ? m : 0.f;
                atomicAdd(&aggr[d * 96 + j], m);
            }
        }
        __syncthreads();  // protect ea_s before next round's overwrite
    }
}

// ---------------------------------------------------------------------------
// Kernel 2: node MLP (fp32). 32-node tile per block, 256 threads.
// h = x + aggr; hm = relu(h@W1+b1); o = hm@W2+b2. Writes o back into the SAME
// buffer as aggr (safe: block reads its rows to LDS first; disjoint rows per
// block). BN per-feature sum/sumsq partials -> global atomics.
// NOTE: aggr/h2 intentionally NOT __restrict__ (they alias).
// ---------------------------------------------------------------------------
__global__ __launch_bounds__(256) void mlp_kernel(
    const float* __restrict__ x, const float* aggr,
    const float* __restrict__ W1g, const float* __restrict__ b1g,
    const float* __restrict__ W2g, const float* __restrict__ b2g,
    float* h2, float* __restrict__ stats) {
    __shared__ float Ws[96 * 96];
    __shared__ float hs[32][97];
    __shared__ float os[32][97];
    __shared__ float b1s[96], b2s[96];

    const int tid = threadIdx.x;
    const int n0 = blockIdx.x * 32;

    for (int i = tid; i < 96 * 96; i += 256) Ws[i] = W1g[i];
    if (tid < 96) {
        b1s[tid] = b1g[tid];
        b2s[tid] = b2g[tid];
    }
    for (int i = tid; i < 32 * 96; i += 256) {
        int n = i / 96, k = i - n * 96;
        float v = 0.f;
        if (n0 + n < N_NODES) {
            int idx = (n0 + n) * 96 + k;
            v = x[idx] + aggr[idx];
        }
        hs[n][k] = v;
    }
    __syncthreads();

    const int n = tid >> 3;   // 0..31
    const int jg = tid & 7;   // 0..7 -> features jg*12 .. jg*12+11
    float acc[12];

    // GEMM1 + ReLU
#pragma unroll
    for (int m = 0; m < 12; ++m) acc[m] = b1s[jg * 12 + m];
    for (int k = 0; k < 96; ++k) {
        float hv = hs[n][k];
#pragma unroll
        for (int m = 0; m < 12; ++m) acc[m] += hv * Ws[k * 96 + jg * 12 + m];
    }
#pragma unroll
    for (int m = 0; m < 12; ++m)
        os[n][jg * 12 + m] = acc[m] > 0.f ? acc[m] : 0.f;
    __syncthreads();

    // swap weights: Ws <- W2
    for (int i = tid; i < 96 * 96; i += 256) Ws[i] = W2g[i];
    __syncthreads();

    // GEMM2
#pragma unroll
    for (int m = 0; m < 12; ++m) acc[m] = b2s[jg * 12 + m];
    for (int k = 0; k < 96; ++k) {
        float hv = os[n][k];
#pragma unroll
        for (int m = 0; m < 12; ++m) acc[m] += hv * Ws[k * 96 + jg * 12 + m];
    }
#pragma unroll
    for (int m = 0; m < 12; ++m) hs[n][jg * 12 + m] = acc[m];
    __syncthreads();

    for (int i = tid; i < 32 * 96; i += 256) {
        int nn = i / 96, k = i - nn * 96;
        if (n0 + nn < N_NODES) h2[(n0 + nn) * 96 + k] = hs[nn][k];
    }
    if (tid < 96) {
        float s = 0.f, s2 = 0.f;
        int nmax = N_NODES - n0;
        if (nmax > 32) nmax = 32;
        for (int nn = 0; nn < nmax; ++nn) {
            float v = hs[nn][tid];
            s += v;
            s2 += v * v;
        }
        atomicAdd(&stats[tid], s);
        atomicAdd(&stats[96 + tid], s2);
    }
}

// ---------------------------------------------------------------------------
// Kernel 3: BN finalize + affine + ReLU -> fp32 out.
// ---------------------------------------------------------------------------
__global__ __launch_bounds__(256) void bn_kernel(
    const float* __restrict__ h2, const float* __restrict__ stats,
    const float* __restrict__ gamma, const float* __restrict__ beta,
    float* __restrict__ out) {
    __shared__ float sc[96], sh[96];
    const int tid = threadIdx.x;
    if (tid < 96) {
        const float inv_n = 1.f / (float)N_NODES;
        float mean = stats[tid] * inv_n;
        float var = stats[96 + tid] * inv_n - mean * mean;
        var = var > 0.f ? var : 0.f;  // guard fp cancellation
        float s = gamma[tid] * rsqrtf(var + BN_EPS);
        sc[tid] = s;
        sh[tid] = beta[tid] - mean * s;
    }
    __syncthreads();
    const int total = N_NODES * 96;
    for (int i = blockIdx.x * blockDim.x + tid; i < total;
         i += gridDim.x * blockDim.x) {
        int j = i % 96;
        float v = h2[i] * sc[j] + sh[j];
        out[i] = v > 0.f ? v : 0.f;
    }
}

// ---------------------------------------------------------------------------
extern "C" void kernel_launch(void* const* d_in, const int* in_sizes, int n_in,
                              void* d_out, int out_size, void* d_ws,
                              size_t ws_size, hipStream_t stream) {
    const float* x     = (const float*)d_in[0];
    const int*   ei    = (const int*)d_in[1];
    const float* ea    = (const float*)d_in[2];
    const float* We    = (const float*)d_in[3];
    const float* be    = (const float*)d_in[4];
    const float* W1    = (const float*)d_in[5];
    const float* b1    = (const float*)d_in[6];
    const float* W2    = (const float*)d_in[7];
    const float* b2    = (const float*)d_in[8];
    const float* gamma = (const float*)d_in[9];
    const float* beta  = (const float*)d_in[10];
    float* out = (float*)d_out;

    float* ws    = (float*)d_ws;
    float* aggr  = ws;              // 4,800,000 floats, reused as h2
    float* stats = ws + WS_STATS;   // 192 floats
    int*   flag  = (int*)(ws + WS_FLAG);

    // zero aggr + stats + flag region (~19.2 MB), capped by ws_size
    size_t zbytes = (size_t)(WS_FLAG + 64) * sizeof(float);
    if (zbytes > ws_size) zbytes = ws_size;
    hipMemsetAsync(d_ws, 0, zbytes, stream);

    detect_kernel<<<1, 256, 0, stream>>>(ei, flag);
    edge_kernel<<<2048, EBLOCK, 0, stream>>>(x, ei, ea, We, be, aggr, flag);
    mlp_kernel<<<(N_NODES + 31) / 32, 256, 0, stream>>>(x, aggr, W1, b1, W2, b2,
                                                        /*h2=*/aggr, stats);
    bn_kernel<<<512, 256, 0, stream>>>(aggr, stats, gamma, beta, out);
}